// Round 4
// baseline (1533.549 us; speedup 1.0000x reference)
//
#include <hip/hip_runtime.h>

#define C_DIM 768
#define K_DIM 2304
#define BZ 16
#define NK (K_DIM / 32)   // 72 K-steps, divisible by 3

typedef short bf16x8 __attribute__((ext_vector_type(8)));
typedef float f32x4 __attribute__((ext_vector_type(4)));

#define GLOBAL_AS __attribute__((address_space(1)))
#define LDS_AS __attribute__((address_space(3)))

// Async global->LDS, 16B per lane. LDS dest is wave-uniform base + lane*16.
__device__ __forceinline__ void async_copy16(const void* g, void* l) {
    __builtin_amdgcn_global_load_lds(
        (GLOBAL_AS void*)(unsigned long long)(uintptr_t)g,
        (LDS_AS void*)(unsigned int)(uintptr_t)l,
        16, 0, 0);
}

__device__ __forceinline__ unsigned short f_to_bf16(float f) {
    union { float f; unsigned int i; } v; v.f = f;
    unsigned int r = v.i + 0x7FFFu + ((v.i >> 16) & 1u);  // RNE
    return (unsigned short)(r >> 16);
}

// Implicit-GEMM conv: out[g, n] = act( sum_k A[g,k] * Bt[n,k] + bias[n] )
// Row g -> sample b = g >> p_shift, position p = g & ((1<<p_shift)-1).
// A window = Abase + b*a_samp_stride + (p*sa)*C_DIM, 3*C_DIM contiguous bf16
// (padded layout: data row p at padded row p+1; pad rows zero).
// MODE 0: conv1 -> gelu -> bf16 to out_bf. MODE 1: conv2 -> fp32 + bf16 next-x.
// MODE 2: conv2 last level -> fp32/new_len only.
//
// R4 structure: block tile 128M x 256N, 4 waves (2m x 2n), wave tile 64x128.
// Rationale (R2/R3 counters): kernel is LDS-read-BW bound; fragment bytes
// per FLOP = WM*WN/(WM+WN). 64x64 -> 32 FLOP/B (MfmaUtil pinned ~32%,
// occupancy-insensitive: R3 cut waves 12->8/CU and util stayed ~28%).
// 64x128 -> 42.7 FLOP/B, 1.33x less LDS traffic per FLOP.
//
// K-loop: 3-buffer software pipeline, prefetch distance 2 steps, counted
// vmcnt(6) (6 copies per stage: 2 A + 4 B) — never a full drain mid-loop.
// T2 LDS swizzle (R2-proven, conflicts == 0): LDS position (r,q) holds global
// chunk q^((r>>1)&3); read XOR folds into a per-thread constant.
template<int MODE>
__global__ __launch_bounds__(256)
void gemm_conv(const unsigned short* __restrict__ Abase,
               const unsigned short* __restrict__ Bt,
               const float* __restrict__ bias,
               const int* __restrict__ lens,
               unsigned short* __restrict__ out_bf,
               float* __restrict__ out_f,
               int M, int p_shift, int a_samp_stride, int sa,
               int o_samp_stride, int len_shift)
{
    // Triple-buffered tiles: A [128][32] (8 KB), B [256][32] (16 KB) -> 72 KB.
    __shared__ __align__(16) short lsA[3][128 * 32];
    __shared__ __align__(16) short lsB[3][256 * 32];

    const int t = threadIdx.x;
    const int lane = t & 63;
    const int wave = t >> 6;

    // T1: bijective XCD-chunked remap (m204 formula). wgid = tile_m*3 + tile_n
    // (n fastest): one XCD's contiguous chunk covers all 3 n-tiles of each of
    // its m-tiles -> A panel fetched into ONE XCD's L2 and reused 3x.
    const int nwg = gridDim.x;
    const int orig = blockIdx.x;
    const int qc = nwg >> 3, rc = nwg & 7;
    const int xcd = orig & 7;
    const int wgid = (xcd < rc ? xcd * (qc + 1)
                               : rc * (qc + 1) + (xcd - rc) * qc) + (orig >> 3);
    const int tile_m = wgid / 3;
    const int tile_n = wgid - tile_m * 3;

    const int Pmask = (1 << p_shift) - 1;

    // Staging: per K-step, A = 512 16B-chunks (2 rounds), B = 1024 (4 rounds).
    // Round it, thread t -> chunk cix = it*256 + t, r = cix>>2, q_pos = cix&3;
    // LDS offset cix*16B (linear, required by global_load_lds). Global source
    // chunk is the swizzle-inverse: q_dat = q_pos ^ ((r>>1)&3).
    const unsigned short* pA[2]; int dofsA[2];
    const unsigned short* pB[4]; int dofsB[4];
#pragma unroll
    for (int it = 0; it < 2; ++it) {
        int cix = it * 256 + t;
        int r = cix >> 2, q4 = cix & 3;
        int qd = q4 ^ ((r >> 1) & 3);                         // T2 source permute
        int g = tile_m * 128 + r; if (g > M - 1) g = M - 1;   // clamp: dup reads safe
        int b = g >> p_shift, p = g & Pmask;
        pA[it] = Abase + (size_t)b * a_samp_stride + (size_t)(p * sa) * C_DIM + qd * 8;
        dofsA[it] = (it * 256 + wave * 64) * 8;  // wave-uniform; lane*16B by HW
    }
#pragma unroll
    for (int it = 0; it < 4; ++it) {
        int cix = it * 256 + t;
        int r = cix >> 2, q4 = cix & 3;
        int qd = q4 ^ ((r >> 1) & 3);                         // T2 source permute
        pB[it] = Bt + (size_t)(tile_n * 256 + r) * K_DIM + qd * 8;
        dofsB[it] = (it * 256 + wave * 64) * 8;
    }

    const f32x4 fzero = {0.0f, 0.0f, 0.0f, 0.0f};
    f32x4 acc[4][8];
#pragma unroll
    for (int i = 0; i < 4; ++i)
#pragma unroll
        for (int j = 0; j < 8; ++j) acc[i][j] = fzero;

    const int wm = (wave >> 1) * 64;      // 2 wave-rows of 64
    const int wn = (wave & 1) * 128;      // 2 wave-cols of 128
    const int lrow = lane & 15;
    // T2 read swizzle folded into the per-thread chunk offset: (row>>1)&3 ==
    // (lrow>>1)&3 because wm/wn and i*16/j*16 don't touch row bits 1..2.
    const int lko = (((lane >> 4) ^ ((lrow >> 1) & 3))) * 8;

    auto stage = [&](int s, int bi) {
        const int koff = s * 32;
#pragma unroll
        for (int it = 0; it < 2; ++it)
            async_copy16(pA[it] + koff, &lsA[bi][dofsA[it]]);
#pragma unroll
        for (int it = 0; it < 4; ++it)
            async_copy16(pB[it] + koff, &lsB[bi][dofsB[it]]);
    };

    auto kstep = [&](int ks, const short* LA, const short* LB, int sbuf) {
        if (ks + 2 < NK) stage(ks + 2, sbuf);       // prefetch 2 steps ahead
        bf16x8 af[4], bfv[8];
#pragma unroll
        for (int i = 0; i < 4; ++i)
            af[i]  = *(const bf16x8*)&LA[(wm + i * 16 + lrow) * 32 + lko];
#pragma unroll
        for (int j = 0; j < 8; ++j)
            bfv[j] = *(const bf16x8*)&LB[(wn + j * 16 + lrow) * 32 + lko];
#pragma unroll
        for (int i = 0; i < 4; ++i)
#pragma unroll
            for (int j = 0; j < 8; ++j)
                acc[i][j] = __builtin_amdgcn_mfma_f32_16x16x32_bf16(af[i], bfv[j], acc[i][j], 0, 0, 0);
        if (ks + 1 < NK) {
            // Drain this wave's LDS reads BEFORE the barrier (buffer anti-dep).
            asm volatile("s_waitcnt lgkmcnt(0)" ::: "memory");
            // Counted vmcnt: retire step ks+1's 6 copies (oldest), keep the
            // 6 just-issued (step ks+2) in flight.
            if (ks + 2 < NK) asm volatile("s_waitcnt vmcnt(6)" ::: "memory");
            else             asm volatile("s_waitcnt vmcnt(0)" ::: "memory");
            __builtin_amdgcn_s_barrier();
            asm volatile("" ::: "memory");          // no mem-op motion across
        }
    };

    // Pipeline prologue: steps 0 and 1 in flight; wait step 0, leave step 1.
    stage(0, 0);
    stage(1, 1);
    asm volatile("s_waitcnt vmcnt(6)" ::: "memory");
    __builtin_amdgcn_s_barrier();
    asm volatile("" ::: "memory");

    // Unrolled x3 so each step's LDS base is a compile-time constant.
    for (int ks = 0; ks < NK; ks += 3) {
        kstep(ks,     lsA[0], lsB[0], 2);
        kstep(ks + 1, lsA[1], lsB[1], 0);
        kstep(ks + 2, lsA[2], lsB[2], 1);
    }

    // Pad-row zeroing folded into the epilogue (256-wide n-tiles now).
    if (MODE == 0 && tile_m == 0) {
        for (int s = t; s < BZ * 256; s += 256) {
            int b = s >> 8, c = tile_n * 256 + (s & 255);
            out_bf[(size_t)b * o_samp_stride + c] = 0;        // hbuf pad row 0
        }
    }
    if (MODE == 1 && tile_m == 0) {
        const int P_out = M >> 4;                              // M = BZ * P_out
        for (int s = t; s < 2 * BZ * 256; s += 256) {
            int rr = s >> 12;                                  // 0 or 1
            int b = (s >> 8) & 15, c = tile_n * 256 + (s & 255);
            size_t row = rr ? (size_t)(P_out + 1) : 0;
            out_bf[(size_t)b * o_samp_stride + row * C_DIM + c] = 0;
        }
    }

    // Epilogue. C/D layout: col = lane&15, row = (lane>>4)*4 + reg.
    int ncol[8]; float bv[8];
#pragma unroll
    for (int j = 0; j < 8; ++j) {
        ncol[j] = tile_n * 256 + wn + j * 16 + lrow;
        bv[j] = bias[ncol[j]];
    }
    const int rowbase = tile_m * 128 + wm + (lane >> 4) * 4;
#pragma unroll
    for (int i = 0; i < 4; ++i) {
#pragma unroll
        for (int rr = 0; rr < 4; ++rr) {
            int g = rowbase + i * 16 + rr;
            if (g >= M) continue;
            int b = g >> p_shift, p = g & Pmask;
            int lim = (lens[b] + (1 << len_shift) - 1) >> len_shift;  // ceil(len/2^s)
            bool valid = p < lim;
#pragma unroll
            for (int j = 0; j < 8; ++j) {
                float v = acc[i][j][rr] + bv[j];
                if (MODE == 0) {
                    float gl = 0.5f * v * (1.0f + erff(v * 0.70710678118654752f));
                    if (!valid) gl = 0.0f;
                    out_bf[(size_t)b * o_samp_stride + (size_t)(p + 1) * C_DIM + ncol[j]] = f_to_bf16(gl);
                } else {
                    if (!valid) v = 0.0f;
                    if (MODE == 2) v *= (1.0f / (float)lim);  // pooled = y / new_len (==1)
                    out_f[(size_t)g * C_DIM + ncol[j]] = v;
                    if (MODE == 1)
                        out_bf[(size_t)b * o_samp_stride + (size_t)(p + 1) * C_DIM + ncol[j]] = f_to_bf16(v);
                }
            }
        }
    }
}

// Bt[n][kk*C+i] = w[n][i][kk], bf16 — GEMM-B in [N, K] so staging matches A's path.
__global__ void prep_weights(const float* __restrict__ w1, const float* __restrict__ w2,
                             unsigned short* __restrict__ Bt1, unsigned short* __restrict__ Bt2) {
    int idx = blockIdx.x * 256 + threadIdx.x;
    if (idx >= C_DIM * K_DIM) return;
    int n = idx / K_DIM, rem = idx - n * K_DIM;
    int kk = rem / C_DIM, i = rem - kk * C_DIM;
    int widx = (n * C_DIM + i) * 3 + kk;
    Bt1[idx] = f_to_bf16(w1[widx]);
    Bt2[idx] = f_to_bf16(w2[widx]);
}

// x0 padded buffer [BZ][2050][C] bf16: pad rows + beyond-length rows zeroed.
__global__ void prep_x0(const float* __restrict__ in, const int* __restrict__ lens,
                        unsigned short* __restrict__ xbuf) {
    int idx = blockIdx.x * 256 + threadIdx.x;
    const int tot = BZ * 2050 * (C_DIM / 4);
    if (idx >= tot) return;
    int c4 = idx % (C_DIM / 4);
    int rest = idx / (C_DIM / 4);
    int r = rest % 2050, b = rest / 2050;
    int p = r - 1;
    ushort4 v = {0, 0, 0, 0};
    if (p >= 0 && p < 2048 && p < lens[b]) {
        const float4 f = *(const float4*)(in + ((size_t)(b * 2048 + p)) * C_DIM + c4 * 4);
        v.x = f_to_bf16(f.x); v.y = f_to_bf16(f.y); v.z = f_to_bf16(f.z); v.w = f_to_bf16(f.w);
    }
    ((ushort4*)xbuf)[idx] = v;
}

// All 11 level masks, straight from lengths. Level-10 mask degenerates to 1.0.
__global__ void write_masks(const int* __restrict__ lens, float* __restrict__ out) {
    int l = blockIdx.y;
    int Pl = 1024 >> l;
    int idx = blockIdx.x * 256 + threadIdx.x;
    if (idx >= BZ * Pl) return;
    int b = idx / Pl, q = idx - b * Pl;
    size_t off = (size_t)BZ * C_DIM * (2048 - (1024 >> l)) + (size_t)BZ * (2048 - (2048 >> l));
    int nl = (lens[b] + (1 << (l + 1)) - 1) >> (l + 1);
    out[off + idx] = (q < nl) ? 1.0f : 0.0f;
}

extern "C" void kernel_launch(void* const* d_in, const int* in_sizes, int n_in,
                              void* d_out, int out_size, void* d_ws, size_t ws_size,
                              hipStream_t stream) {
    const float* seq = (const float*)d_in[0];
    const int* lens = (const int*)d_in[1];
    const float* w1 = (const float*)d_in[2];
    const float* b1 = (const float*)d_in[3];
    const float* w2 = (const float*)d_in[4];
    const float* b2 = (const float*)d_in[5];
    float* out = (float*)d_out;
    char* ws = (char*)d_ws;

    // ws layout (bytes): xbuf 0..50.4MB, hbuf @52MiB, Bt1 @104MiB, Bt2 @108MiB
    unsigned short* xbuf = (unsigned short*)(ws);
    unsigned short* hbuf = (unsigned short*)(ws + (size_t)(52u << 20));
    unsigned short* Bt1  = (unsigned short*)(ws + (size_t)(104u << 20));
    unsigned short* Bt2  = (unsigned short*)(ws + (size_t)(108u << 20));

    prep_weights<<<(C_DIM * K_DIM + 255) / 256, 256, 0, stream>>>(w1, w2, Bt1, Bt2);
    {
        int tot = BZ * 2050 * (C_DIM / 4);
        prep_x0<<<(tot + 255) / 256, 256, 0, stream>>>(seq, lens, xbuf);
    }
    write_masks<<<dim3(64, 11), 256, 0, stream>>>(lens, out);

    size_t y_off = 0;
    for (int l = 0; l < 11; ++l) {
        int P_in = 2048 >> l, P_out = P_in >> 1;
        int M1 = BZ * P_in, M2 = BZ * P_out;
        int sh_in = __builtin_ctz((unsigned)P_in), sh_out = __builtin_ctz((unsigned)P_out);
        int a_str = (P_in + 2) * C_DIM;   // padded sample stride of this level's x / h
        int x_str = (P_out + 2) * C_DIM;  // padded sample stride of next level's x
        int g1 = 3 * ((M1 + 127) / 128), g2 = 3 * ((M2 + 127) / 128);

        // conv1 + GELU + mask -> hbuf (padded, bf16); also zeroes hbuf pad row 0
        gemm_conv<0><<<g1, 256, 0, stream>>>(xbuf, Bt1, b1, lens, hbuf, nullptr,
                                             M1, sh_in, a_str, 1, a_str, l);
        // conv2 + mask -> d_out fp32 chunk (+ bf16 next-level x incl. pad rows)
        if (l < 10)
            gemm_conv<1><<<g2, 256, 0, stream>>>(hbuf, Bt2, b2, lens, xbuf, out + y_off,
                                                 M2, sh_out, a_str, 2, x_str, l + 1);
        else
            gemm_conv<2><<<g2, 256, 0, stream>>>(hbuf, Bt2, b2, lens, xbuf, out + y_off,
                                                 M2, sh_out, a_str, 2, x_str, l + 1);
        y_off += (size_t)M2 * C_DIM + (size_t)M2;  // y chunk then mask chunk
    }
}

// Round 5
// 1089.613 us; speedup vs baseline: 1.4074x; 1.4074x over previous
//
#include <hip/hip_runtime.h>

#define C_DIM 768
#define K_DIM 2304
#define BZ 16
#define NK (K_DIM / 32)   // 72 K-chunks of 32

typedef short bf16x8 __attribute__((ext_vector_type(8)));
typedef float f32x4 __attribute__((ext_vector_type(4)));

#define GLOBAL_AS __attribute__((address_space(1)))
#define LDS_AS __attribute__((address_space(3)))

// Async global->LDS, 16B per lane. LDS dest is wave-uniform base + lane*16.
__device__ __forceinline__ void async_copy16(const void* g, void* l) {
    __builtin_amdgcn_global_load_lds(
        (GLOBAL_AS void*)(unsigned long long)(uintptr_t)g,
        (LDS_AS void*)(unsigned int)(uintptr_t)l,
        16, 0, 0);
}

__device__ __forceinline__ unsigned short f_to_bf16(float f) {
    union { float f; unsigned int i; } v; v.f = f;
    unsigned int r = v.i + 0x7FFFu + ((v.i >> 16) & 1u);  // RNE
    return (unsigned short)(r >> 16);
}

// Implicit-GEMM conv: out[g, n] = act( sum_k A[g,k] * Bt[n,k] + bias[n] )
// Row g -> sample b = g >> p_shift, position p = g & ((1<<p_shift)-1).
// A window = Abase + b*a_samp_stride + (p*sa)*C_DIM, 3*C_DIM contiguous bf16
// (padded layout: data row p at padded row p+1; pad rows zero).
// MODE 0: conv1 -> gelu -> bf16. MODE 1: conv2 -> fp32 + bf16 next-x.
// MODE 2: conv2 last level -> fp32/new_len only.
//
// Block tile 128x128 (R2-proven; R3/R4 taught: do NOT trade occupancy on the
// big dispatches). 4 waves (2m x 2n), wave tile 64x64.
//
// NSUB = K-chunks (of 32) per staged buffer:
//  NSUB=1: R2 config. 72 steps, 48 KB LDS, ~3 blk/CU. For big grids (M>4096).
//  NSUB=2: 36 steps, 96 KB LDS, 1 blk/CU. For small grids (M<=4096, where
//          grid <= 192 blocks <= #CUs so LDS-occupancy is FREE and the cost
//          is the SERIAL K-chain: halving step count ~halves dispatch time).
// Both: 3-buffer pipeline, prefetch 2 steps ahead, counted vmcnt (never 0
// mid-loop), raw s_barrier (no __syncthreads = no vmcnt(0) drain).
//
// T2 LDS swizzle (R2-measured conflicts == 0), generalized per row width:
//  NSUB=1 (64B rows, slot=(r&1)*4+q): q_dat = q_pos ^ ((r>>1)&3)
//  NSUB=2 (128B rows, slot=q):        q_dat = q_pos ^ (r&7)
// Source-permuted at setup (global_load_lds dest must stay linear); read
// applies the same involution, folded into per-thread constants.
template<int MODE, int NSUB>
__global__ __launch_bounds__(256)
void gemm_conv(const unsigned short* __restrict__ Abase,
               const unsigned short* __restrict__ Bt,
               const float* __restrict__ bias,
               const int* __restrict__ lens,
               unsigned short* __restrict__ out_bf,
               float* __restrict__ out_f,
               int M, int p_shift, int a_samp_stride, int sa,
               int o_samp_stride, int len_shift)
{
    constexpr int W   = 32 * NSUB;        // LDS row width (shorts)
    constexpr int NS  = NK / NSUB;        // serial K-steps
    constexpr int NRD = 2 * NSUB;         // staging rounds per matrix

    __shared__ __align__(16) short lsA[3][128 * W];
    __shared__ __align__(16) short lsB[3][128 * W];

    const int t = threadIdx.x;
    const int lane = t & 63;
    const int wave = t >> 6;

    // T1: bijective XCD-chunked remap (m204). wgid = tile_m*6 + tile_n
    // (n fastest): one XCD's chunk covers all 6 n-tiles of each m-tile.
    const int nwg = gridDim.x;
    const int orig = blockIdx.x;
    const int qc = nwg >> 3, rc = nwg & 7;
    const int xcd = orig & 7;
    const int wgid = (xcd < rc ? xcd * (qc + 1)
                               : rc * (qc + 1) + (xcd - rc) * qc) + (orig >> 3);
    const int tile_m = wgid / 6;
    const int tile_n = wgid - tile_m * 6;

    const int Pmask = (1 << p_shift) - 1;

    // Staging: round it, thread t -> chunk cix = it*256 + t; LDS offset
    // cix*16B (linear). Row r = cix / (W/8); within-row chunk q_pos; global
    // source chunk is the swizzle-inverse q_dat.
    const unsigned short* pA[NRD]; int dofsA[NRD];
    const unsigned short* pB[NRD]; int dofsB[NRD];
#pragma unroll
    for (int it = 0; it < NRD; ++it) {
        int cix = it * 256 + t;
        int r, qd;
        if constexpr (NSUB == 1) { r = cix >> 2; int q = cix & 3; qd = q ^ ((r >> 1) & 3); }
        else                     { r = cix >> 3; int q = cix & 7; qd = q ^ (r & 7); }
        int g = tile_m * 128 + r; if (g > M - 1) g = M - 1;   // clamp: dup reads safe
        int b = g >> p_shift, p = g & Pmask;
        pA[it] = Abase + (size_t)b * a_samp_stride + (size_t)(p * sa) * C_DIM + qd * 8;
        pB[it] = Bt + (size_t)(tile_n * 128 + r) * K_DIM + qd * 8;
        dofsA[it] = (it * 256 + wave * 64) * 8;  // wave-uniform; lane*16B by HW
        dofsB[it] = dofsA[it];
    }

    const f32x4 fzero = {0.0f, 0.0f, 0.0f, 0.0f};
    f32x4 acc[4][4];
#pragma unroll
    for (int i = 0; i < 4; ++i)
#pragma unroll
        for (int j = 0; j < 4; ++j) acc[i][j] = fzero;

    const int wm = (wave >> 1) * 64, wn = (wave & 1) * 64;
    const int lrow = lane & 15;
    // Read-side swizzle, per sub-chunk, folded to per-thread constants
    // ((r & needed-bits) == (lrow & needed-bits): wm, i*16 don't touch them).
    int lkos[NSUB];
#pragma unroll
    for (int sub = 0; sub < NSUB; ++sub) {
        if constexpr (NSUB == 1)
            lkos[sub] = ((lane >> 4) ^ ((lrow >> 1) & 3)) * 8;
        else
            lkos[sub] = ((sub * 4 + (lane >> 4)) ^ (lrow & 7)) * 8;
    }

    auto stage = [&](int s, int bi) {
        const int koff = s * W;
#pragma unroll
        for (int it = 0; it < NRD; ++it) {
            async_copy16(pA[it] + koff, &lsA[bi][dofsA[it]]);
            async_copy16(pB[it] + koff, &lsB[bi][dofsB[it]]);
        }
    };

    auto kstep = [&](int ks, const short* LA, const short* LB, int sbuf) {
        if (ks + 2 < NS) stage(ks + 2, sbuf);       // prefetch 2 steps ahead
#pragma unroll
        for (int sub = 0; sub < NSUB; ++sub) {
            bf16x8 af[4], bfv[4];
#pragma unroll
            for (int i = 0; i < 4; ++i) {
                af[i]  = *(const bf16x8*)&LA[(wm + i * 16 + lrow) * W + lkos[sub]];
                bfv[i] = *(const bf16x8*)&LB[(wn + i * 16 + lrow) * W + lkos[sub]];
            }
#pragma unroll
            for (int i = 0; i < 4; ++i)
#pragma unroll
                for (int j = 0; j < 4; ++j)
                    acc[i][j] = __builtin_amdgcn_mfma_f32_16x16x32_bf16(af[i], bfv[j], acc[i][j], 0, 0, 0);
        }
        if (ks + 1 < NS) {
            // Drain this wave's LDS reads BEFORE the barrier (buffer anti-dep).
            asm volatile("s_waitcnt lgkmcnt(0)" ::: "memory");
            // Counted vmcnt: retire step ks+1's copies (oldest), keep the
            // just-issued step-ks+2 copies in flight.
            if (ks + 2 < NS) {
                if constexpr (NSUB == 1) asm volatile("s_waitcnt vmcnt(4)" ::: "memory");
                else                     asm volatile("s_waitcnt vmcnt(8)" ::: "memory");
            } else {
                asm volatile("s_waitcnt vmcnt(0)" ::: "memory");
            }
            __builtin_amdgcn_s_barrier();
            asm volatile("" ::: "memory");          // no mem-op motion across
        }
    };

    // Pipeline prologue: steps 0 and 1 in flight; wait step 0, leave step 1.
    stage(0, 0);
    stage(1, 1);
    if constexpr (NSUB == 1) asm volatile("s_waitcnt vmcnt(4)" ::: "memory");
    else                     asm volatile("s_waitcnt vmcnt(8)" ::: "memory");
    __builtin_amdgcn_s_barrier();
    asm volatile("" ::: "memory");

    // Unrolled x3 so each step's LDS base is a compile-time constant.
    for (int ks = 0; ks < NS; ks += 3) {
        kstep(ks,     lsA[0], lsB[0], 2);
        kstep(ks + 1, lsA[1], lsB[1], 0);
        kstep(ks + 2, lsA[2], lsB[2], 1);
    }

    // Pad-row zeroing folded into the epilogue.
    if (MODE == 0 && tile_m == 0) {
        for (int s = t; s < BZ * 128; s += 256) {
            int b = s >> 7, c = tile_n * 128 + (s & 127);
            out_bf[(size_t)b * o_samp_stride + c] = 0;        // hbuf pad row 0
        }
    }
    if (MODE == 1 && tile_m == 0) {
        const int P_out = M >> 4;                              // M = BZ * P_out
        for (int s = t; s < 2 * BZ * 128; s += 256) {
            int rr = s >> 11;                                  // 0 or 1
            int b = (s >> 7) & 15, c = tile_n * 128 + (s & 127);
            size_t row = rr ? (size_t)(P_out + 1) : 0;
            out_bf[(size_t)b * o_samp_stride + row * C_DIM + c] = 0;
        }
    }

    // Epilogue. C/D layout: col = lane&15, row = (lane>>4)*4 + reg.
    int ncol[4]; float bv[4];
#pragma unroll
    for (int j = 0; j < 4; ++j) {
        ncol[j] = tile_n * 128 + wn + j * 16 + lrow;
        bv[j] = bias[ncol[j]];
    }
    const int rowbase = tile_m * 128 + wm + (lane >> 4) * 4;
#pragma unroll
    for (int i = 0; i < 4; ++i) {
#pragma unroll
        for (int rr = 0; rr < 4; ++rr) {
            int g = rowbase + i * 16 + rr;
            if (g >= M) continue;
            int b = g >> p_shift, p = g & Pmask;
            int lim = (lens[b] + (1 << len_shift) - 1) >> len_shift;  // ceil(len/2^s)
            bool valid = p < lim;
#pragma unroll
            for (int j = 0; j < 4; ++j) {
                float v = acc[i][j][rr] + bv[j];
                if (MODE == 0) {
                    float gl = 0.5f * v * (1.0f + erff(v * 0.70710678118654752f));
                    if (!valid) gl = 0.0f;
                    out_bf[(size_t)b * o_samp_stride + (size_t)(p + 1) * C_DIM + ncol[j]] = f_to_bf16(gl);
                } else {
                    if (!valid) v = 0.0f;
                    if (MODE == 2) v *= (1.0f / (float)lim);  // pooled = y / new_len (==1)
                    out_f[(size_t)g * C_DIM + ncol[j]] = v;
                    if (MODE == 1)
                        out_bf[(size_t)b * o_samp_stride + (size_t)(p + 1) * C_DIM + ncol[j]] = f_to_bf16(v);
                }
            }
        }
    }
}

// Bt[n][kk*C+i] = w[n][i][kk], bf16 — GEMM-B in [N, K] so staging matches A's path.
__global__ void prep_weights(const float* __restrict__ w1, const float* __restrict__ w2,
                             unsigned short* __restrict__ Bt1, unsigned short* __restrict__ Bt2) {
    int idx = blockIdx.x * 256 + threadIdx.x;
    if (idx >= C_DIM * K_DIM) return;
    int n = idx / K_DIM, rem = idx - n * K_DIM;
    int kk = rem / C_DIM, i = rem - kk * C_DIM;
    int widx = (n * C_DIM + i) * 3 + kk;
    Bt1[idx] = f_to_bf16(w1[widx]);
    Bt2[idx] = f_to_bf16(w2[widx]);
}

// x0 padded buffer [BZ][2050][C] bf16: pad rows + beyond-length rows zeroed.
__global__ void prep_x0(const float* __restrict__ in, const int* __restrict__ lens,
                        unsigned short* __restrict__ xbuf) {
    int idx = blockIdx.x * 256 + threadIdx.x;
    const int tot = BZ * 2050 * (C_DIM / 4);
    if (idx >= tot) return;
    int c4 = idx % (C_DIM / 4);
    int rest = idx / (C_DIM / 4);
    int r = rest % 2050, b = rest / 2050;
    int p = r - 1;
    ushort4 v = {0, 0, 0, 0};
    if (p >= 0 && p < 2048 && p < lens[b]) {
        const float4 f = *(const float4*)(in + ((size_t)(b * 2048 + p)) * C_DIM + c4 * 4);
        v.x = f_to_bf16(f.x); v.y = f_to_bf16(f.y); v.z = f_to_bf16(f.z); v.w = f_to_bf16(f.w);
    }
    ((ushort4*)xbuf)[idx] = v;
}

// All 11 level masks, straight from lengths. Level-10 mask degenerates to 1.0.
__global__ void write_masks(const int* __restrict__ lens, float* __restrict__ out) {
    int l = blockIdx.y;
    int Pl = 1024 >> l;
    int idx = blockIdx.x * 256 + threadIdx.x;
    if (idx >= BZ * Pl) return;
    int b = idx / Pl, q = idx - b * Pl;
    size_t off = (size_t)BZ * C_DIM * (2048 - (1024 >> l)) + (size_t)BZ * (2048 - (2048 >> l));
    int nl = (lens[b] + (1 << (l + 1)) - 1) >> (l + 1);
    out[off + idx] = (q < nl) ? 1.0f : 0.0f;
}

extern "C" void kernel_launch(void* const* d_in, const int* in_sizes, int n_in,
                              void* d_out, int out_size, void* d_ws, size_t ws_size,
                              hipStream_t stream) {
    const float* seq = (const float*)d_in[0];
    const int* lens = (const int*)d_in[1];
    const float* w1 = (const float*)d_in[2];
    const float* b1 = (const float*)d_in[3];
    const float* w2 = (const float*)d_in[4];
    const float* b2 = (const float*)d_in[5];
    float* out = (float*)d_out;
    char* ws = (char*)d_ws;

    // ws layout (bytes): xbuf 0..50.4MB, hbuf @52MiB, Bt1 @104MiB, Bt2 @108MiB
    unsigned short* xbuf = (unsigned short*)(ws);
    unsigned short* hbuf = (unsigned short*)(ws + (size_t)(52u << 20));
    unsigned short* Bt1  = (unsigned short*)(ws + (size_t)(104u << 20));
    unsigned short* Bt2  = (unsigned short*)(ws + (size_t)(108u << 20));

    prep_weights<<<(C_DIM * K_DIM + 255) / 256, 256, 0, stream>>>(w1, w2, Bt1, Bt2);
    {
        int tot = BZ * 2050 * (C_DIM / 4);
        prep_x0<<<(tot + 255) / 256, 256, 0, stream>>>(seq, lens, xbuf);
    }
    write_masks<<<dim3(64, 11), 256, 0, stream>>>(lens, out);

    size_t y_off = 0;
    for (int l = 0; l < 11; ++l) {
        int P_in = 2048 >> l, P_out = P_in >> 1;
        int M1 = BZ * P_in, M2 = BZ * P_out;
        int sh_in = __builtin_ctz((unsigned)P_in), sh_out = __builtin_ctz((unsigned)P_out);
        int a_str = (P_in + 2) * C_DIM;   // padded sample stride of this level's x / h
        int x_str = (P_out + 2) * C_DIM;  // padded sample stride of next level's x
        int g1 = 6 * ((M1 + 127) / 128), g2 = 6 * ((M2 + 127) / 128);

        // conv1 + GELU + mask -> hbuf (padded, bf16); also zeroes hbuf pad row 0.
        // M<=4096: grid <= 192 blocks (grid-starved) -> NSUB=2 halves the
        // serial K-chain; LDS-occupancy cost is free at 1 blk/CU anyway.
        if (M1 > 4096)
            gemm_conv<0, 1><<<g1, 256, 0, stream>>>(xbuf, Bt1, b1, lens, hbuf, nullptr,
                                                    M1, sh_in, a_str, 1, a_str, l);
        else
            gemm_conv<0, 2><<<g1, 256, 0, stream>>>(xbuf, Bt1, b1, lens, hbuf, nullptr,
                                                    M1, sh_in, a_str, 1, a_str, l);
        // conv2 + mask -> d_out fp32 chunk (+ bf16 next-level x incl. pad rows)
        if (l < 10) {
            if (M2 > 4096)
                gemm_conv<1, 1><<<g2, 256, 0, stream>>>(hbuf, Bt2, b2, lens, xbuf, out + y_off,
                                                        M2, sh_out, a_str, 2, x_str, l + 1);
            else
                gemm_conv<1, 2><<<g2, 256, 0, stream>>>(hbuf, Bt2, b2, lens, xbuf, out + y_off,
                                                        M2, sh_out, a_str, 2, x_str, l + 1);
        } else {
            gemm_conv<2, 2><<<g2, 256, 0, stream>>>(hbuf, Bt2, b2, lens, xbuf, out + y_off,
                                                    M2, sh_out, a_str, 2, x_str, l + 1);
        }
        y_off += (size_t)M2 * C_DIM + (size_t)M2;  // y chunk then mask chunk
    }
}